// Round 8
// baseline (303.104 us; speedup 1.0000x reference)
//
#include <hip/hip_runtime.h>

#define NBLK 1024
#define NTHR 256
#define H1_BINS 2048
#define H1_SHIFT 20
#define NCOPY 4
#define H2_BINS (1u << H1_SHIFT)      // 1048576
#define H2_MASK (H2_BINS - 1u)
#define CHUNK 2048
#define NCHUNK ((int)(H2_BINS / CHUNK))   // 512

// ws layout (bytes):
//   CTRL     [0, 256)
//   H1       [1024, 9216)            2048 x u32
//   p1part   [16384, 32768)          NBLK x 2 doubles
//   p2part   [32768, 40960)          NBLK doubles
//   chunkCnt [40960, 45056)          512 x u64
//   chunkW   [45056, 49152)          512 x double
//   dumH1    [49152, 57344)          2048 x u32   (ablation scratch, never read)
//   dumP1    [57344, 65536)          NBLK doubles (ablation scratch, never read)
//   H2       [65536, 4259840)        2^20 x u32
//   lossBits [4259840, +4n)          n x u32
#define OFF_H1       1024
#define OFF_P1PART   16384
#define OFF_P2PART   32768
#define OFF_CCNT     40960
#define OFF_CW       45056
#define OFF_DH1      49152
#define OFF_DP1      57344
#define OFF_H2       65536
#define OFF_LOSS     4259840

#define LN2F 0.69314718055994531f

__device__ __forceinline__ void elem_compute(float pp, int tt, float mm,
                                             float& loss, bool& pos, bool& neg) {
    bool isz = (tt == 0);
    float x = isz ? pp : (1.0f - pp);
    float lr = fminf(-__log2f(x) * LN2F, 100.0f);
    loss = lr * mm;
    float tm = isz ? mm : 0.0f;
    pos = (tm == 1.0f);
    neg = (tm == 0.0f);
}

// ---------------- ablation kernels (write only dummy/overwritten state) ----------------

__global__ __launch_bounds__(NTHR) void abl1_load(const float* __restrict__ pred,
                                                  const int* __restrict__ targ,
                                                  const float* __restrict__ mask, int n) {
    int nv = n >> 2;
    int gstride = gridDim.x * blockDim.x;
    const float4* p4 = (const float4*)pred;
    const int4*   t4 = (const int4*)targ;
    const float4* m4 = (const float4*)mask;
    for (int i = blockIdx.x * blockDim.x + threadIdx.x; i < nv; i += gstride) {
        float4 p = p4[i]; int4 t = t4[i]; float4 m = m4[i];
        asm volatile("" :: "v"(p.x), "v"(p.y), "v"(p.z), "v"(p.w));
        asm volatile("" :: "v"(t.x), "v"(t.y), "v"(t.z), "v"(t.w));
        asm volatile("" :: "v"(m.x), "v"(m.y), "v"(m.z), "v"(m.w));
    }
}

__global__ __launch_bounds__(NTHR) void abl2_comp(const float* __restrict__ pred,
                                                  const int* __restrict__ targ,
                                                  const float* __restrict__ mask, int n,
                                                  double* __restrict__ dumP1) {
    __shared__ double sredd[NTHR];
    int tid = threadIdx.x;
    float totLoss = 0.f, posLoss = 0.f;
    unsigned posCnt = 0, negCnt = 0;
    int nv = n >> 2;
    int gstride = gridDim.x * blockDim.x;
    const float4* p4 = (const float4*)pred;
    const int4*   t4 = (const int4*)targ;
    const float4* m4 = (const float4*)mask;
    for (int i = blockIdx.x * blockDim.x + tid; i < nv; i += gstride) {
        float4 p = p4[i]; int4 t = t4[i]; float4 m = m4[i];
        float pa[4] = {p.x, p.y, p.z, p.w};
        int   ta[4] = {t.x, t.y, t.z, t.w};
        float ma[4] = {m.x, m.y, m.z, m.w};
        #pragma unroll
        for (int j = 0; j < 4; ++j) {
            float loss; bool pos, neg;
            elem_compute(pa[j], ta[j], ma[j], loss, pos, neg);
            totLoss += loss;
            if (pos) { posCnt++; posLoss += loss; }
            unsigned u = __float_as_uint(loss);
            if (u & 0x80000000u) u = 0u;
            if (!neg) u = 0x80000000u; else negCnt++;
            asm volatile("" :: "v"(u));           // keep bit-pattern path live
        }
    }
    asm volatile("" :: "v"(posLoss), "v"(posCnt), "v"(negCnt));
    sredd[tid] = (double)totLoss; __syncthreads();
    for (int s = NTHR / 2; s > 0; s >>= 1) { if (tid < s) sredd[tid] += sredd[tid + s]; __syncthreads(); }
    if (tid == 0) dumP1[blockIdx.x] = sredd[0];
}

__global__ __launch_bounds__(NTHR) void abl3_hist(const float* __restrict__ pred,
                                                  const int* __restrict__ targ,
                                                  const float* __restrict__ mask, int n,
                                                  unsigned* __restrict__ dumH1,
                                                  double* __restrict__ dumP1) {
    __shared__ unsigned shist[H1_BINS * NCOPY];
    __shared__ double sredd[NTHR];
    int tid = threadIdx.x;
    int copyIdx = tid & (NCOPY - 1);
    for (int i = tid; i < H1_BINS * NCOPY; i += NTHR) shist[i] = 0;
    __syncthreads();
    float totLoss = 0.f, posLoss = 0.f;
    unsigned posCnt = 0, negCnt = 0;
    int nv = n >> 2;
    int gstride = gridDim.x * blockDim.x;
    const float4* p4 = (const float4*)pred;
    const int4*   t4 = (const int4*)targ;
    const float4* m4 = (const float4*)mask;
    for (int i = blockIdx.x * blockDim.x + tid; i < nv; i += gstride) {
        float4 p = p4[i]; int4 t = t4[i]; float4 m = m4[i];
        float pa[4] = {p.x, p.y, p.z, p.w};
        int   ta[4] = {t.x, t.y, t.z, t.w};
        float ma[4] = {m.x, m.y, m.z, m.w};
        #pragma unroll
        for (int j = 0; j < 4; ++j) {
            float loss; bool pos, neg;
            elem_compute(pa[j], ta[j], ma[j], loss, pos, neg);
            totLoss += loss;
            if (pos) { posCnt++; posLoss += loss; }
            unsigned u = __float_as_uint(loss);
            if (u & 0x80000000u) u = 0u;
            if (neg) { negCnt++; atomicAdd(&shist[(u >> H1_SHIFT) * NCOPY + copyIdx], 1u); }
        }
    }
    __syncthreads();
    for (int b = tid; b < H1_BINS; b += NTHR) {
        uint4 v = *(const uint4*)&shist[b * NCOPY];
        unsigned c = v.x + v.y + v.z + v.w;
        if (c) atomicAdd(&dumH1[b], c);
    }
    asm volatile("" :: "v"(posLoss), "v"(posCnt), "v"(negCnt));
    sredd[tid] = (double)totLoss; __syncthreads();
    for (int s = NTHR / 2; s > 0; s >>= 1) { if (tid < s) sredd[tid] += sredd[tid + s]; __syncthreads(); }
    if (tid == 0) dumP1[blockIdx.x] = sredd[0];
}

__global__ __launch_bounds__(NTHR) void abl4_store(const float* __restrict__ pred,
                                                   const int* __restrict__ targ,
                                                   const float* __restrict__ mask, int n,
                                                   unsigned* __restrict__ lossOut,
                                                   double* __restrict__ dumP1) {
    __shared__ double sredd[NTHR];
    int tid = threadIdx.x;
    float totLoss = 0.f, posLoss = 0.f;
    unsigned posCnt = 0, negCnt = 0;
    int nv = n >> 2;
    int gstride = gridDim.x * blockDim.x;
    const float4* p4 = (const float4*)pred;
    const int4*   t4 = (const int4*)targ;
    const float4* m4 = (const float4*)mask;
    uint4* l4 = (uint4*)lossOut;
    for (int i = blockIdx.x * blockDim.x + tid; i < nv; i += gstride) {
        float4 p = p4[i]; int4 t = t4[i]; float4 m = m4[i];
        float pa[4] = {p.x, p.y, p.z, p.w};
        int   ta[4] = {t.x, t.y, t.z, t.w};
        float ma[4] = {m.x, m.y, m.z, m.w};
        unsigned ua[4];
        #pragma unroll
        for (int j = 0; j < 4; ++j) {
            float loss; bool pos, neg;
            elem_compute(pa[j], ta[j], ma[j], loss, pos, neg);
            totLoss += loss;
            if (pos) { posCnt++; posLoss += loss; }
            unsigned u = __float_as_uint(loss);
            if (u & 0x80000000u) u = 0u;
            if (!neg) u = 0x80000000u; else negCnt++;
            ua[j] = u;
        }
        uint4 st; st.x = ua[0]; st.y = ua[1]; st.z = ua[2]; st.w = ua[3];
        l4[i] = st;
    }
    asm volatile("" :: "v"(posLoss), "v"(posCnt), "v"(negCnt));
    sredd[tid] = (double)totLoss; __syncthreads();
    for (int s = NTHR / 2; s > 0; s >>= 1) { if (tid < s) sredd[tid] += sredd[tid + s]; __syncthreads(); }
    if (tid == 0) dumP1[blockIdx.x] = sredd[0];
}

// full work, software-pipelined (next loads issued before current compute)
__global__ __launch_bounds__(NTHR) void abl5_pipe(const float* __restrict__ pred,
                                                  const int* __restrict__ targ,
                                                  const float* __restrict__ mask, int n,
                                                  unsigned* __restrict__ dumH1,
                                                  double* __restrict__ dumP1,
                                                  unsigned* __restrict__ lossOut) {
    __shared__ unsigned shist[H1_BINS * NCOPY];
    __shared__ double sredd[NTHR];
    int tid = threadIdx.x;
    int copyIdx = tid & (NCOPY - 1);
    for (int i = tid; i < H1_BINS * NCOPY; i += NTHR) shist[i] = 0;
    __syncthreads();
    float totLoss = 0.f, posLoss = 0.f;
    unsigned posCnt = 0, negCnt = 0;
    int nv = n >> 2;
    int gstride = gridDim.x * blockDim.x;
    const float4* p4 = (const float4*)pred;
    const int4*   t4 = (const int4*)targ;
    const float4* m4 = (const float4*)mask;
    uint4* l4 = (uint4*)lossOut;
    int i = blockIdx.x * blockDim.x + tid;
    float4 cp = {0,0,0,0}, cm = {0,0,0,0}; int4 ct = {1,1,1,1};
    if (i < nv) { cp = p4[i]; ct = t4[i]; cm = m4[i]; }
    while (i < nv) {
        int inext = i + gstride;
        float4 np = {0,0,0,0}, nm = {0,0,0,0}; int4 nt = {1,1,1,1};
        if (inext < nv) { np = p4[inext]; nt = t4[inext]; nm = m4[inext]; }
        float pa[4] = {cp.x, cp.y, cp.z, cp.w};
        int   ta[4] = {ct.x, ct.y, ct.z, ct.w};
        float ma[4] = {cm.x, cm.y, cm.z, cm.w};
        unsigned ua[4];
        #pragma unroll
        for (int j = 0; j < 4; ++j) {
            float loss; bool pos, neg;
            elem_compute(pa[j], ta[j], ma[j], loss, pos, neg);
            totLoss += loss;
            if (pos) { posCnt++; posLoss += loss; }
            unsigned u = __float_as_uint(loss);
            if (u & 0x80000000u) u = 0u;
            if (neg) { negCnt++; atomicAdd(&shist[(u >> H1_SHIFT) * NCOPY + copyIdx], 1u); }
            else u = 0x80000000u;
            ua[j] = u;
        }
        uint4 st; st.x = ua[0]; st.y = ua[1]; st.z = ua[2]; st.w = ua[3];
        l4[i] = st;
        cp = np; ct = nt; cm = nm; i = inext;
    }
    __syncthreads();
    for (int b = tid; b < H1_BINS; b += NTHR) {
        uint4 v = *(const uint4*)&shist[b * NCOPY];
        unsigned c = v.x + v.y + v.z + v.w;
        if (c) atomicAdd(&dumH1[b], c);
    }
    asm volatile("" :: "v"(posLoss), "v"(posCnt), "v"(negCnt));
    sredd[tid] = (double)totLoss; __syncthreads();
    for (int s = NTHR / 2; s > 0; s >>= 1) { if (tid < s) sredd[tid] += sredd[tid + s]; __syncthreads(); }
    if (tid == 0) dumP1[blockIdx.x] = sredd[0];
}

// ---------------- real pipeline (identical to R5) ----------------

template <bool STORE>
__global__ __launch_bounds__(NTHR) void pass1(const float* __restrict__ pred,
                                              const int* __restrict__ targ,
                                              const float* __restrict__ mask,
                                              int n, unsigned* __restrict__ gH1,
                                              unsigned long long* __restrict__ ctrl,
                                              double* __restrict__ p1part,
                                              unsigned* __restrict__ lossOut) {
    __shared__ unsigned shist[H1_BINS * NCOPY];
    __shared__ double sredd[NTHR];
    __shared__ unsigned sredu[NTHR];
    int tid = threadIdx.x;
    int copyIdx = tid & (NCOPY - 1);
    for (int i = tid; i < H1_BINS * NCOPY; i += NTHR) shist[i] = 0;
    __syncthreads();

    float posLoss = 0.f, totLoss = 0.f;
    unsigned posCnt = 0, negCnt = 0;

    int nv = n >> 2;
    int gstride = gridDim.x * blockDim.x;
    int g0 = blockIdx.x * blockDim.x + tid;
    const float4* p4 = (const float4*)pred;
    const int4*   t4 = (const int4*)targ;
    const float4* m4 = (const float4*)mask;
    uint4* l4 = (uint4*)lossOut;
    for (int i = g0; i < nv; i += gstride) {
        float4 p = p4[i]; int4 t = t4[i]; float4 m = m4[i];
        float pa[4] = {p.x, p.y, p.z, p.w};
        int   ta[4] = {t.x, t.y, t.z, t.w};
        float ma[4] = {m.x, m.y, m.z, m.w};
        unsigned ua[4];
        #pragma unroll
        for (int j = 0; j < 4; ++j) {
            float loss; bool pos, neg;
            elem_compute(pa[j], ta[j], ma[j], loss, pos, neg);
            totLoss += loss;
            if (pos) { posCnt++; posLoss += loss; }
            unsigned u = __float_as_uint(loss);
            if (u & 0x80000000u) u = 0u;
            if (neg) {
                negCnt++;
                atomicAdd(&shist[(u >> H1_SHIFT) * NCOPY + copyIdx], 1u);
            } else {
                u = 0x80000000u;
            }
            ua[j] = u;
        }
        if (STORE) {
            uint4 st; st.x = ua[0]; st.y = ua[1]; st.z = ua[2]; st.w = ua[3];
            l4[i] = st;
        }
    }
    for (int i = (nv << 2) + g0; i < n; i += gstride) {
        float loss; bool pos, neg;
        elem_compute(pred[i], targ[i], mask[i], loss, pos, neg);
        totLoss += loss;
        if (pos) { posCnt++; posLoss += loss; }
        unsigned u = __float_as_uint(loss);
        if (u & 0x80000000u) u = 0u;
        if (neg) {
            negCnt++;
            atomicAdd(&shist[(u >> H1_SHIFT) * NCOPY + copyIdx], 1u);
        } else {
            u = 0x80000000u;
        }
        if (STORE) lossOut[i] = u;
    }
    __syncthreads();
    for (int b = tid; b < H1_BINS; b += NTHR) {
        uint4 v = *(const uint4*)&shist[b * NCOPY];
        unsigned c = v.x + v.y + v.z + v.w;
        if (c) atomicAdd(&gH1[b], c);
    }
    sredd[tid] = (double)posLoss; __syncthreads();
    for (int s = NTHR / 2; s > 0; s >>= 1) { if (tid < s) sredd[tid] += sredd[tid + s]; __syncthreads(); }
    if (tid == 0) p1part[2 * blockIdx.x] = sredd[0];
    __syncthreads();
    sredd[tid] = (double)totLoss; __syncthreads();
    for (int s = NTHR / 2; s > 0; s >>= 1) { if (tid < s) sredd[tid] += sredd[tid + s]; __syncthreads(); }
    if (tid == 0) p1part[2 * blockIdx.x + 1] = sredd[0];
    __syncthreads();
    sredu[tid] = posCnt; __syncthreads();
    for (int s = NTHR / 2; s > 0; s >>= 1) { if (tid < s) sredu[tid] += sredu[tid + s]; __syncthreads(); }
    if (tid == 0) atomicAdd(&ctrl[0], (unsigned long long)sredu[0]);
    __syncthreads();
    sredu[tid] = negCnt; __syncthreads();
    for (int s = NTHR / 2; s > 0; s >>= 1) { if (tid < s) sredu[tid] += sredu[tid + s]; __syncthreads(); }
    if (tid == 0) atomicAdd(&ctrl[1], (unsigned long long)sredu[0]);
}

__global__ __launch_bounds__(1024) void findbin(const unsigned* __restrict__ gH1,
                                                unsigned long long* __restrict__ ctrl,
                                                const double* __restrict__ p1part) {
    __shared__ double sd[1024];
    __shared__ unsigned long long ss[1024];
    int tid = threadIdx.x;
    sd[tid] = p1part[2 * tid]; __syncthreads();
    for (int s = 512; s > 0; s >>= 1) { if (tid < s) sd[tid] += sd[tid + s]; __syncthreads(); }
    double posLoss = sd[0]; __syncthreads();
    sd[tid] = p1part[2 * tid + 1]; __syncthreads();
    for (int s = 512; s > 0; s >>= 1) { if (tid < s) sd[tid] += sd[tid + s]; __syncthreads(); }
    double totLoss = sd[0]; __syncthreads();

    unsigned long long posCnt = ctrl[0];
    unsigned long long negCnt = ctrl[1];
    unsigned long long k = posCnt * 5ULL;
    if (k > negCnt) k = negCnt;

    int base = tid * 2;
    unsigned h0 = gH1[base], h1 = gH1[base + 1];
    ss[tid] = (unsigned long long)h0 + h1; __syncthreads();
    for (int d = 1; d < 1024; d <<= 1) {
        unsigned long long add = (tid + d < 1024) ? ss[tid + d] : 0ULL;
        __syncthreads();
        ss[tid] += add;
        __syncthreads();
    }
    unsigned long long run = (tid == 1023) ? 0ULL : ss[tid + 1];
    if (k > 0) {
        if (run < k && k <= run + h1) {
            ctrl[2] = (unsigned long long)(base + 1);
            ctrl[3] = k - run;
        }
        run += h1;
        if (run < k && k <= run + h0) {
            ctrl[2] = (unsigned long long)base;
            ctrl[3] = k - run;
        }
    } else if (tid == 0) {
        ctrl[2] = (unsigned long long)H1_BINS;
        ctrl[3] = 0;
    }
    if (tid == 0) {
        ctrl[4] = k;
        ((double*)ctrl)[5] = posLoss;
        ((double*)ctrl)[6] = totLoss;
    }
}

__global__ __launch_bounds__(NTHR) void pass2s(const unsigned* __restrict__ lossBits,
                                               int n,
                                               const unsigned long long* __restrict__ ctrl,
                                               unsigned* __restrict__ gH2,
                                               double* __restrict__ p2part) {
    __shared__ double sredd[NTHR];
    int tid = threadIdx.x;
    unsigned b1 = (unsigned)ctrl[2];
    float acc = 0.f;
    int nv = n >> 2;
    int gstride = gridDim.x * blockDim.x;
    int g0 = blockIdx.x * blockDim.x + tid;
    const uint4* l4 = (const uint4*)lossBits;
    for (int i = g0; i < nv; i += gstride) {
        uint4 v = l4[i];
        unsigned ua[4] = {v.x, v.y, v.z, v.w};
        #pragma unroll
        for (int j = 0; j < 4; ++j) {
            unsigned u = ua[j];
            if (!(u & 0x80000000u)) {
                unsigned bin = u >> H1_SHIFT;
                if (bin > b1) acc += __uint_as_float(u);
                else if (bin == b1) atomicAdd(&gH2[u & H2_MASK], 1u);
            }
        }
    }
    for (int i = (nv << 2) + g0; i < n; i += gstride) {
        unsigned u = lossBits[i];
        if (!(u & 0x80000000u)) {
            unsigned bin = u >> H1_SHIFT;
            if (bin > b1) acc += __uint_as_float(u);
            else if (bin == b1) atomicAdd(&gH2[u & H2_MASK], 1u);
        }
    }
    sredd[tid] = (double)acc; __syncthreads();
    for (int s = NTHR / 2; s > 0; s >>= 1) { if (tid < s) sredd[tid] += sredd[tid + s]; __syncthreads(); }
    if (tid == 0) p2part[blockIdx.x] = sredd[0];
}

__global__ __launch_bounds__(NTHR) void pass2(const float* __restrict__ pred,
                                              const int* __restrict__ targ,
                                              const float* __restrict__ mask,
                                              int n,
                                              const unsigned long long* __restrict__ ctrl,
                                              unsigned* __restrict__ gH2,
                                              double* __restrict__ p2part) {
    __shared__ double sredd[NTHR];
    int tid = threadIdx.x;
    unsigned b1 = (unsigned)ctrl[2];
    float acc = 0.f;
    int nv = n >> 2;
    int gstride = gridDim.x * blockDim.x;
    int g0 = blockIdx.x * blockDim.x + tid;
    const float4* p4 = (const float4*)pred;
    const int4*   t4 = (const int4*)targ;
    const float4* m4 = (const float4*)mask;
    for (int i = g0; i < nv; i += gstride) {
        float4 p = p4[i]; int4 t = t4[i]; float4 m = m4[i];
        float pa[4] = {p.x, p.y, p.z, p.w};
        int   ta[4] = {t.x, t.y, t.z, t.w};
        float ma[4] = {m.x, m.y, m.z, m.w};
        #pragma unroll
        for (int j = 0; j < 4; ++j) {
            float loss; bool pos, neg;
            elem_compute(pa[j], ta[j], ma[j], loss, pos, neg);
            if (neg) {
                unsigned u = __float_as_uint(loss);
                if (u & 0x80000000u) u = 0u;
                unsigned bin = u >> H1_SHIFT;
                if (bin > b1) acc += loss;
                else if (bin == b1) atomicAdd(&gH2[u & H2_MASK], 1u);
            }
        }
    }
    for (int i = (nv << 2) + g0; i < n; i += gstride) {
        float loss; bool pos, neg;
        elem_compute(pred[i], targ[i], mask[i], loss, pos, neg);
        if (neg) {
            unsigned u = __float_as_uint(loss);
            if (u & 0x80000000u) u = 0u;
            unsigned bin = u >> H1_SHIFT;
            if (bin > b1) acc += loss;
            else if (bin == b1) atomicAdd(&gH2[u & H2_MASK], 1u);
        }
    }
    sredd[tid] = (double)acc; __syncthreads();
    for (int s = NTHR / 2; s > 0; s >>= 1) { if (tid < s) sredd[tid] += sredd[tid + s]; __syncthreads(); }
    if (tid == 0) p2part[blockIdx.x] = sredd[0];
}

__global__ __launch_bounds__(256) void chunkscan(const unsigned* __restrict__ gH2,
                                                 const unsigned long long* __restrict__ ctrl,
                                                 unsigned long long* __restrict__ chunkCnt,
                                                 double* __restrict__ chunkW) {
    __shared__ unsigned long long sc[256];
    __shared__ double sw[256];
    int tid = threadIdx.x;
    unsigned b1 = (unsigned)ctrl[2];
    int base = blockIdx.x * CHUNK;
    unsigned long long cnt = 0; double w = 0.0;
    if (b1 < H1_BINS) {
        for (int i = tid; i < CHUNK; i += 256) {
            unsigned c = gH2[base + i];
            if (c) {
                float L = __uint_as_float((b1 << H1_SHIFT) | (unsigned)(base + i));
                cnt += c;
                w += (double)c * (double)L;
            }
        }
    }
    sc[tid] = cnt; sw[tid] = w; __syncthreads();
    for (int s = 128; s > 0; s >>= 1) {
        if (tid < s) { sc[tid] += sc[tid + s]; sw[tid] += sw[tid + s]; }
        __syncthreads();
    }
    if (tid == 0) { chunkCnt[blockIdx.x] = sc[0]; chunkW[blockIdx.x] = sw[0]; }
}

__global__ __launch_bounds__(512) void finalize(const unsigned* __restrict__ gH2,
                                                const unsigned long long* __restrict__ ctrl,
                                                const double* __restrict__ p2part,
                                                const unsigned long long* __restrict__ chunkCnt,
                                                const double* __restrict__ chunkW,
                                                float* __restrict__ out, int n) {
    __shared__ double sd[512];
    __shared__ unsigned long long sc[512];
    __shared__ double sw[512];
    __shared__ int s_cstar;
    __shared__ unsigned long long s_rem;
    __shared__ double s_wAbove;
    __shared__ double s_res;
    int tid = threadIdx.x;

    sd[tid] = p2part[tid] + p2part[tid + 512]; __syncthreads();
    for (int s = 256; s > 0; s >>= 1) { if (tid < s) sd[tid] += sd[tid + s]; __syncthreads(); }
    double sumAbove = sd[0]; __syncthreads();

    unsigned long long posCnt = ctrl[0];
    unsigned long long b1 = ctrl[2];
    unsigned long long need = ctrl[3];
    unsigned long long k = ctrl[4];
    double posLoss = ((const double*)ctrl)[5];
    double totLoss = ((const double*)ctrl)[6];

    double negLoss = sumAbove;

    if (need > 0) {
        if (tid == 0) { s_cstar = 0; s_rem = 1; s_wAbove = 0.0; s_res = 0.0; }
        unsigned long long myc = chunkCnt[tid];
        double myw = chunkW[tid];
        sc[tid] = myc; sw[tid] = myw; __syncthreads();
        for (int d = 1; d < 512; d <<= 1) {
            unsigned long long ac = (tid + d < 512) ? sc[tid + d] : 0ULL;
            double aw = (tid + d < 512) ? sw[tid + d] : 0.0;
            __syncthreads();
            sc[tid] += ac; sw[tid] += aw;
            __syncthreads();
        }
        unsigned long long afterC = (tid == 511) ? 0ULL : sc[tid + 1];
        double afterW = (tid == 511) ? 0.0 : sw[tid + 1];
        if (afterC < need && need <= afterC + myc) {
            s_cstar = tid; s_rem = need - afterC; s_wAbove = afterW;
        }
        __syncthreads();
        int cstar = s_cstar;
        unsigned long long rem = s_rem;
        double wAbove = s_wAbove;
        __syncthreads();

        int pb = cstar * CHUNK + 4 * tid;
        unsigned c[4]; double L[4];
        unsigned long long tot = 0; double wtot = 0.0;
        #pragma unroll
        for (int j = 0; j < 4; ++j) {
            c[j] = gH2[pb + j];
            L[j] = (double)__uint_as_float(((unsigned)b1 << H1_SHIFT) | (unsigned)(pb + j));
            tot += c[j];
            wtot += (double)c[j] * L[j];
        }
        sc[tid] = tot; sw[tid] = wtot;
        __syncthreads();
        for (int d = 1; d < 512; d <<= 1) {
            unsigned long long ac = (tid + d < 512) ? sc[tid + d] : 0ULL;
            double aw = (tid + d < 512) ? sw[tid + d] : 0.0;
            __syncthreads();
            sc[tid] += ac; sw[tid] += aw;
            __syncthreads();
        }
        unsigned long long run = (tid == 511) ? 0ULL : sc[tid + 1];
        double wrun = (tid == 511) ? 0.0 : sw[tid + 1];
        #pragma unroll
        for (int j = 3; j >= 0; --j) {
            if (run < rem && rem <= run + c[j]) {
                s_res = wrun + (double)(rem - run) * L[j];
            }
            run += c[j];
            wrun += (double)c[j] * L[j];
        }
        __syncthreads();
        negLoss += wAbove + s_res;
    }

    if (tid == 0) {
        double result;
        if (posCnt == 0) {
            result = totLoss / (double)n;
        } else {
            result = (posLoss + negLoss) / ((double)posCnt + (double)k + 1e-8);
        }
        out[0] = (float)result;
    }
}

extern "C" void kernel_launch(void* const* d_in, const int* in_sizes, int n_in,
                              void* d_out, int out_size, void* d_ws, size_t ws_size,
                              hipStream_t stream) {
    const float* pred = (const float*)d_in[0];
    const int*   targ = (const int*)d_in[1];
    const float* mask = (const float*)d_in[2];
    int n = in_sizes[0];

    char* ws = (char*)d_ws;
    unsigned long long* ctrl = (unsigned long long*)ws;
    unsigned* gH1 = (unsigned*)(ws + OFF_H1);
    double* p1part = (double*)(ws + OFF_P1PART);
    double* p2part = (double*)(ws + OFF_P2PART);
    unsigned long long* chunkCnt = (unsigned long long*)(ws + OFF_CCNT);
    double* chunkW = (double*)(ws + OFF_CW);
    unsigned* dumH1 = (unsigned*)(ws + OFF_DH1);
    double* dumP1 = (double*)(ws + OFF_DP1);
    unsigned* gH2 = (unsigned*)(ws + OFF_H2);
    unsigned* lossBits = (unsigned*)(ws + OFF_LOSS);

    bool store = ws_size >= (size_t)OFF_LOSS + (size_t)n * 4ull;

    (void)hipMemsetAsync(ws, 0, OFF_H1 + H1_BINS * 4, stream);
    (void)hipMemsetAsync(ws + OFF_H2, 0, H2_BINS * 4, stream);

    // ---- ablation dispatches (outputs dummy or overwritten; diagnostic only) ----
    abl1_load<<<NBLK, NTHR, 0, stream>>>(pred, targ, mask, n);
    abl2_comp<<<NBLK, NTHR, 0, stream>>>(pred, targ, mask, n, dumP1);
    abl3_hist<<<NBLK, NTHR, 0, stream>>>(pred, targ, mask, n, dumH1, dumP1);
    if (store) {
        abl4_store<<<NBLK, NTHR, 0, stream>>>(pred, targ, mask, n, lossBits, dumP1);
        abl5_pipe<<<NBLK, NTHR, 0, stream>>>(pred, targ, mask, n, dumH1, dumP1, lossBits);
    }

    // ---- real pipeline ----
    if (store) {
        pass1<true><<<NBLK, NTHR, 0, stream>>>(pred, targ, mask, n, gH1, ctrl, p1part, lossBits);
        findbin<<<1, 1024, 0, stream>>>(gH1, ctrl, p1part);
        pass2s<<<NBLK, NTHR, 0, stream>>>(lossBits, n, ctrl, gH2, p2part);
    } else {
        pass1<false><<<NBLK, NTHR, 0, stream>>>(pred, targ, mask, n, gH1, ctrl, p1part, lossBits);
        findbin<<<1, 1024, 0, stream>>>(gH1, ctrl, p1part);
        pass2<<<NBLK, NTHR, 0, stream>>>(pred, targ, mask, n, ctrl, gH2, p2part);
    }
    chunkscan<<<NCHUNK, 256, 0, stream>>>(gH2, ctrl, chunkCnt, chunkW);
    finalize<<<1, 512, 0, stream>>>(gH2, ctrl, p2part, chunkCnt, chunkW, (float*)d_out, n);
}

// Round 9
// 100.730 us; speedup vs baseline: 3.0091x; 3.0091x over previous
//
#include <hip/hip_runtime.h>

#define NBLK 1024
#define NTHR 256
#define H1_BINS 4096
#define H1_SHIFT 19
#define H2_BINS (1u << H1_SHIFT)      // 524288
#define H2_MASK (H2_BINS - 1u)
#define CHUNK 1024
#define NCHUNK ((int)(H2_BINS / CHUNK))   // 512
#define UNROLL 4
#define TILE (NTHR * UNROLL)          // 1024 float4-groups per tile

// ws layout (bytes):  (same as R4)
//   CTRL     [0, 256)
//   H1       [1024, 17408)           4096 x u32
//   H2       [32768, 2129920)        524288 x u32
//   p1part   [2129920, 2146304)      NBLK x 2 doubles
//   p2part   [2146304, 2154496)      NBLK doubles
//   chunkCnt [2154496, 2158592)      512 x u64
//   chunkW   [2158592, 2162688)      512 x double
//   lossBits [4194304, 4194304+4n)   n x u32 (only if ws_size permits)
#define OFF_H1       1024
#define OFF_H2       32768
#define OFF_P1PART   2129920
#define OFF_P2PART   2146304
#define OFF_CCNT     2154496
#define OFF_CW       2158592
#define OFF_LOSS     4194304
#define MEMSET_BYTES 2129920   // ctrl + H1 + H2

#define LN2F 0.69314718055994531f

// loss = min(-log(x), 100) * m  with x = (t==0 ? p : 1-p); single v_log_f32.
__device__ __forceinline__ void elem_compute(float pp, int tt, float mm,
                                             float& loss, bool& pos, bool& neg) {
    bool isz = (tt == 0);
    float x = isz ? pp : (1.0f - pp);
    float lr = fminf(-__log2f(x) * LN2F, 100.0f);
    loss = lr * mm;
    float tm = isz ? mm : 0.0f;
    pos = (tm == 1.0f);
    neg = (tm == 0.0f);
}

template <bool STORE>
__global__ __launch_bounds__(NTHR) void pass1(const float* __restrict__ pred,
                                              const int* __restrict__ targ,
                                              const float* __restrict__ mask,
                                              int n, unsigned* __restrict__ gH1,
                                              unsigned long long* __restrict__ ctrl,
                                              double* __restrict__ p1part,
                                              unsigned* __restrict__ lossOut) {
    __shared__ unsigned shist[H1_BINS];
    __shared__ double sredd[NTHR];
    __shared__ unsigned sredu[NTHR];
    int tid = threadIdx.x;
    for (int i = tid; i < H1_BINS; i += NTHR) shist[i] = 0;
    __syncthreads();

    float posLoss = 0.f, totLoss = 0.f;
    unsigned posCnt = 0, negCnt = 0;

    int nv = n >> 2;
    const float4* p4 = (const float4*)pred;
    const int4*   t4 = (const int4*)targ;
    const float4* m4 = (const float4*)mask;
    uint4* l4 = (uint4*)lossOut;

    // contiguous per-block tiles, 4x unrolled loads (12 loads in flight/thread)
    int tiles = (nv + TILE - 1) / TILE;
    int perblk = (tiles + NBLK - 1) / NBLK;
    int tstart = blockIdx.x * perblk;
    int tend = tstart + perblk; if (tend > tiles) tend = tiles;

    for (int tt = tstart; tt < tend; ++tt) {
        int g = tt * TILE + tid;
        bool full = (tt * TILE + TILE) <= nv;
        float4 p[UNROLL]; int4 t[UNROLL]; float4 m[UNROLL];
        bool ok[UNROLL];
        if (full) {
            #pragma unroll
            for (int k = 0; k < UNROLL; ++k) {
                p[k] = p4[g + k * NTHR]; t[k] = t4[g + k * NTHR]; m[k] = m4[g + k * NTHR];
                ok[k] = true;
            }
        } else {
            #pragma unroll
            for (int k = 0; k < UNROLL; ++k) {
                ok[k] = (g + k * NTHR) < nv;
                if (ok[k]) { p[k] = p4[g + k * NTHR]; t[k] = t4[g + k * NTHR]; m[k] = m4[g + k * NTHR]; }
            }
        }
        #pragma unroll
        for (int k = 0; k < UNROLL; ++k) {
            if (!ok[k]) continue;
            float pa[4] = {p[k].x, p[k].y, p[k].z, p[k].w};
            int   ta[4] = {t[k].x, t[k].y, t[k].z, t[k].w};
            float ma[4] = {m[k].x, m[k].y, m[k].z, m[k].w};
            unsigned ua[4];
            #pragma unroll
            for (int j = 0; j < 4; ++j) {
                float loss; bool pos, neg;
                elem_compute(pa[j], ta[j], ma[j], loss, pos, neg);
                totLoss += loss;
                if (pos) { posCnt++; posLoss += loss; }
                unsigned u = __float_as_uint(loss);
                if (u & 0x80000000u) u = 0u;
                if (neg) {
                    negCnt++;
                    atomicAdd(&shist[u >> H1_SHIFT], 1u);
                } else {
                    u = 0x80000000u;
                }
                ua[j] = u;
            }
            if (STORE) {
                uint4 st; st.x = ua[0]; st.y = ua[1]; st.z = ua[2]; st.w = ua[3];
                l4[g + k * NTHR] = st;
            }
        }
    }
    // scalar tail (n % 4)
    for (int i = (nv << 2) + blockIdx.x * blockDim.x + tid; i < n; i += gridDim.x * blockDim.x) {
        float loss; bool pos, neg;
        elem_compute(pred[i], targ[i], mask[i], loss, pos, neg);
        totLoss += loss;
        if (pos) { posCnt++; posLoss += loss; }
        unsigned u = __float_as_uint(loss);
        if (u & 0x80000000u) u = 0u;
        if (neg) {
            negCnt++;
            atomicAdd(&shist[u >> H1_SHIFT], 1u);
        } else {
            u = 0x80000000u;
        }
        if (STORE) lossOut[i] = u;
    }
    __syncthreads();
    for (int i = tid; i < H1_BINS; i += NTHR) {
        unsigned c = shist[i];
        if (c) atomicAdd(&gH1[i], c);
    }
    sredd[tid] = (double)posLoss; __syncthreads();
    for (int s = NTHR / 2; s > 0; s >>= 1) { if (tid < s) sredd[tid] += sredd[tid + s]; __syncthreads(); }
    if (tid == 0) p1part[2 * blockIdx.x] = sredd[0];
    __syncthreads();
    sredd[tid] = (double)totLoss; __syncthreads();
    for (int s = NTHR / 2; s > 0; s >>= 1) { if (tid < s) sredd[tid] += sredd[tid + s]; __syncthreads(); }
    if (tid == 0) p1part[2 * blockIdx.x + 1] = sredd[0];
    __syncthreads();
    sredu[tid] = posCnt; __syncthreads();
    for (int s = NTHR / 2; s > 0; s >>= 1) { if (tid < s) sredu[tid] += sredu[tid + s]; __syncthreads(); }
    if (tid == 0) atomicAdd(&ctrl[0], (unsigned long long)sredu[0]);
    __syncthreads();
    sredu[tid] = negCnt; __syncthreads();
    for (int s = NTHR / 2; s > 0; s >>= 1) { if (tid < s) sredu[tid] += sredu[tid + s]; __syncthreads(); }
    if (tid == 0) atomicAdd(&ctrl[1], (unsigned long long)sredu[0]);
}

__global__ __launch_bounds__(1024) void findbin(const unsigned* __restrict__ gH1,
                                                unsigned long long* __restrict__ ctrl,
                                                const double* __restrict__ p1part) {
    __shared__ double sd[1024];
    __shared__ unsigned long long ss[1024];
    int tid = threadIdx.x;
    sd[tid] = p1part[2 * tid]; __syncthreads();
    for (int s = 512; s > 0; s >>= 1) { if (tid < s) sd[tid] += sd[tid + s]; __syncthreads(); }
    double posLoss = sd[0]; __syncthreads();
    sd[tid] = p1part[2 * tid + 1]; __syncthreads();
    for (int s = 512; s > 0; s >>= 1) { if (tid < s) sd[tid] += sd[tid + s]; __syncthreads(); }
    double totLoss = sd[0]; __syncthreads();

    unsigned long long posCnt = ctrl[0];
    unsigned long long negCnt = ctrl[1];
    unsigned long long k = posCnt * 5ULL;
    if (k > negCnt) k = negCnt;

    int base = tid * 4;
    unsigned h0 = gH1[base], h1 = gH1[base + 1], h2 = gH1[base + 2], h3 = gH1[base + 3];
    unsigned long long mysum = (unsigned long long)h0 + h1 + h2 + h3;
    ss[tid] = mysum; __syncthreads();
    for (int d = 1; d < 1024; d <<= 1) {
        unsigned long long add = (tid + d < 1024) ? ss[tid + d] : 0ULL;
        __syncthreads();
        ss[tid] += add;
        __syncthreads();
    }
    unsigned long long run = (tid == 1023) ? 0ULL : ss[tid + 1];
    if (k > 0) {
        unsigned hh[4] = {h3, h2, h1, h0};
        int off[4] = {3, 2, 1, 0};
        #pragma unroll
        for (int j = 0; j < 4; ++j) {
            unsigned long long c = hh[j];
            if (run < k && k <= run + c) {
                ctrl[2] = (unsigned long long)(base + off[j]);
                ctrl[3] = k - run;
            }
            run += c;
        }
    } else if (tid == 0) {
        ctrl[2] = (unsigned long long)H1_BINS;
        ctrl[3] = 0;
    }
    if (tid == 0) {
        ctrl[4] = k;
        ((double*)ctrl)[5] = posLoss;
        ((double*)ctrl)[6] = totLoss;
    }
}

// pass2 from stored loss bits: contiguous tiles + 4x unroll
__global__ __launch_bounds__(NTHR) void pass2s(const unsigned* __restrict__ lossBits,
                                               int n,
                                               const unsigned long long* __restrict__ ctrl,
                                               unsigned* __restrict__ gH2,
                                               double* __restrict__ p2part) {
    __shared__ double sredd[NTHR];
    int tid = threadIdx.x;
    unsigned b1 = (unsigned)ctrl[2];
    float acc = 0.f;
    int nv = n >> 2;
    const uint4* l4 = (const uint4*)lossBits;

    int tiles = (nv + TILE - 1) / TILE;
    int perblk = (tiles + NBLK - 1) / NBLK;
    int tstart = blockIdx.x * perblk;
    int tend = tstart + perblk; if (tend > tiles) tend = tiles;

    for (int tt = tstart; tt < tend; ++tt) {
        int g = tt * TILE + tid;
        bool full = (tt * TILE + TILE) <= nv;
        uint4 v[UNROLL]; bool ok[UNROLL];
        if (full) {
            #pragma unroll
            for (int k = 0; k < UNROLL; ++k) { v[k] = l4[g + k * NTHR]; ok[k] = true; }
        } else {
            #pragma unroll
            for (int k = 0; k < UNROLL; ++k) {
                ok[k] = (g + k * NTHR) < nv;
                if (ok[k]) v[k] = l4[g + k * NTHR];
            }
        }
        #pragma unroll
        for (int k = 0; k < UNROLL; ++k) {
            if (!ok[k]) continue;
            unsigned ua[4] = {v[k].x, v[k].y, v[k].z, v[k].w};
            #pragma unroll
            for (int j = 0; j < 4; ++j) {
                unsigned u = ua[j];
                if (!(u & 0x80000000u)) {
                    unsigned bin = u >> H1_SHIFT;
                    if (bin > b1) acc += __uint_as_float(u);
                    else if (bin == b1) atomicAdd(&gH2[u & H2_MASK], 1u);
                }
            }
        }
    }
    for (int i = (nv << 2) + blockIdx.x * blockDim.x + tid; i < n; i += gridDim.x * blockDim.x) {
        unsigned u = lossBits[i];
        if (!(u & 0x80000000u)) {
            unsigned bin = u >> H1_SHIFT;
            if (bin > b1) acc += __uint_as_float(u);
            else if (bin == b1) atomicAdd(&gH2[u & H2_MASK], 1u);
        }
    }
    sredd[tid] = (double)acc; __syncthreads();
    for (int s = NTHR / 2; s > 0; s >>= 1) { if (tid < s) sredd[tid] += sredd[tid + s]; __syncthreads(); }
    if (tid == 0) p2part[blockIdx.x] = sredd[0];
}

// fallback pass2: recompute losses from inputs
__global__ __launch_bounds__(NTHR) void pass2(const float* __restrict__ pred,
                                              const int* __restrict__ targ,
                                              const float* __restrict__ mask,
                                              int n,
                                              const unsigned long long* __restrict__ ctrl,
                                              unsigned* __restrict__ gH2,
                                              double* __restrict__ p2part) {
    __shared__ double sredd[NTHR];
    int tid = threadIdx.x;
    unsigned b1 = (unsigned)ctrl[2];
    float acc = 0.f;
    int nv = n >> 2;
    int gstride = gridDim.x * blockDim.x;
    int g0 = blockIdx.x * blockDim.x + tid;
    const float4* p4 = (const float4*)pred;
    const int4*   t4 = (const int4*)targ;
    const float4* m4 = (const float4*)mask;
    for (int i = g0; i < nv; i += gstride) {
        float4 p = p4[i]; int4 t = t4[i]; float4 m = m4[i];
        float pa[4] = {p.x, p.y, p.z, p.w};
        int   ta[4] = {t.x, t.y, t.z, t.w};
        float ma[4] = {m.x, m.y, m.z, m.w};
        #pragma unroll
        for (int j = 0; j < 4; ++j) {
            float loss; bool pos, neg;
            elem_compute(pa[j], ta[j], ma[j], loss, pos, neg);
            if (neg) {
                unsigned u = __float_as_uint(loss);
                if (u & 0x80000000u) u = 0u;
                unsigned bin = u >> H1_SHIFT;
                if (bin > b1) acc += loss;
                else if (bin == b1) atomicAdd(&gH2[u & H2_MASK], 1u);
            }
        }
    }
    for (int i = (nv << 2) + g0; i < n; i += gstride) {
        float loss; bool pos, neg;
        elem_compute(pred[i], targ[i], mask[i], loss, pos, neg);
        if (neg) {
            unsigned u = __float_as_uint(loss);
            if (u & 0x80000000u) u = 0u;
            unsigned bin = u >> H1_SHIFT;
            if (bin > b1) acc += loss;
            else if (bin == b1) atomicAdd(&gH2[u & H2_MASK], 1u);
        }
    }
    sredd[tid] = (double)acc; __syncthreads();
    for (int s = NTHR / 2; s > 0; s >>= 1) { if (tid < s) sredd[tid] += sredd[tid + s]; __syncthreads(); }
    if (tid == 0) p2part[blockIdx.x] = sredd[0];
}

__global__ __launch_bounds__(256) void chunkscan(const unsigned* __restrict__ gH2,
                                                 const unsigned long long* __restrict__ ctrl,
                                                 unsigned long long* __restrict__ chunkCnt,
                                                 double* __restrict__ chunkW) {
    __shared__ unsigned long long sc[256];
    __shared__ double sw[256];
    int tid = threadIdx.x;
    unsigned b1 = (unsigned)ctrl[2];
    int base = blockIdx.x * CHUNK;
    unsigned long long cnt = 0; double w = 0.0;
    if (b1 < H1_BINS) {
        for (int i = tid; i < CHUNK; i += 256) {
            unsigned c = gH2[base + i];
            if (c) {
                float L = __uint_as_float((b1 << H1_SHIFT) | (unsigned)(base + i));
                cnt += c;
                w += (double)c * (double)L;
            }
        }
    }
    sc[tid] = cnt; sw[tid] = w; __syncthreads();
    for (int s = 128; s > 0; s >>= 1) {
        if (tid < s) { sc[tid] += sc[tid + s]; sw[tid] += sw[tid + s]; }
        __syncthreads();
    }
    if (tid == 0) { chunkCnt[blockIdx.x] = sc[0]; chunkW[blockIdx.x] = sw[0]; }
}

__global__ __launch_bounds__(512) void finalize(const unsigned* __restrict__ gH2,
                                                const unsigned long long* __restrict__ ctrl,
                                                const double* __restrict__ p2part,
                                                const unsigned long long* __restrict__ chunkCnt,
                                                const double* __restrict__ chunkW,
                                                float* __restrict__ out, int n) {
    __shared__ double sd[512];
    __shared__ unsigned long long sc[512];
    __shared__ double sw[512];
    __shared__ int s_cstar;
    __shared__ unsigned long long s_rem;
    __shared__ double s_wAbove;
    __shared__ double s_res;
    int tid = threadIdx.x;

    sd[tid] = p2part[tid] + p2part[tid + 512]; __syncthreads();
    for (int s = 256; s > 0; s >>= 1) { if (tid < s) sd[tid] += sd[tid + s]; __syncthreads(); }
    double sumAbove = sd[0]; __syncthreads();

    unsigned long long posCnt = ctrl[0];
    unsigned long long b1 = ctrl[2];
    unsigned long long need = ctrl[3];
    unsigned long long k = ctrl[4];
    double posLoss = ((const double*)ctrl)[5];
    double totLoss = ((const double*)ctrl)[6];

    double negLoss = sumAbove;

    if (need > 0) {
        if (tid == 0) { s_cstar = 0; s_rem = 1; s_wAbove = 0.0; s_res = 0.0; }
        unsigned long long myc = chunkCnt[tid];
        double myw = chunkW[tid];
        sc[tid] = myc; sw[tid] = myw; __syncthreads();
        for (int d = 1; d < 512; d <<= 1) {
            unsigned long long ac = (tid + d < 512) ? sc[tid + d] : 0ULL;
            double aw = (tid + d < 512) ? sw[tid + d] : 0.0;
            __syncthreads();
            sc[tid] += ac; sw[tid] += aw;
            __syncthreads();
        }
        unsigned long long afterC = (tid == 511) ? 0ULL : sc[tid + 1];
        double afterW = (tid == 511) ? 0.0 : sw[tid + 1];
        if (afterC < need && need <= afterC + myc) {
            s_cstar = tid; s_rem = need - afterC; s_wAbove = afterW;
        }
        __syncthreads();
        int cstar = s_cstar;
        unsigned long long rem = s_rem;
        double wAbove = s_wAbove;
        __syncthreads();

        int pb = cstar * CHUNK + 2 * tid;
        unsigned c0 = gH2[pb], c1 = gH2[pb + 1];
        float L0 = __uint_as_float(((unsigned)b1 << H1_SHIFT) | (unsigned)pb);
        float L1 = __uint_as_float(((unsigned)b1 << H1_SHIFT) | (unsigned)(pb + 1));
        sc[tid] = (unsigned long long)c0 + c1;
        sw[tid] = (double)c0 * (double)L0 + (double)c1 * (double)L1;
        __syncthreads();
        for (int d = 1; d < 512; d <<= 1) {
            unsigned long long ac = (tid + d < 512) ? sc[tid + d] : 0ULL;
            double aw = (tid + d < 512) ? sw[tid + d] : 0.0;
            __syncthreads();
            sc[tid] += ac; sw[tid] += aw;
            __syncthreads();
        }
        unsigned long long run = (tid == 511) ? 0ULL : sc[tid + 1];
        double wrun = (tid == 511) ? 0.0 : sw[tid + 1];
        if (run < rem && rem <= run + c1) {
            s_res = wrun + (double)(rem - run) * (double)L1;
        }
        run += c1; wrun += (double)c1 * (double)L1;
        if (run < rem && rem <= run + c0) {
            s_res = wrun + (double)(rem - run) * (double)L0;
        }
        __syncthreads();
        negLoss += wAbove + s_res;
    }

    if (tid == 0) {
        double result;
        if (posCnt == 0) {
            result = totLoss / (double)n;
        } else {
            result = (posLoss + negLoss) / ((double)posCnt + (double)k + 1e-8);
        }
        out[0] = (float)result;
    }
}

extern "C" void kernel_launch(void* const* d_in, const int* in_sizes, int n_in,
                              void* d_out, int out_size, void* d_ws, size_t ws_size,
                              hipStream_t stream) {
    const float* pred = (const float*)d_in[0];
    const int*   targ = (const int*)d_in[1];
    const float* mask = (const float*)d_in[2];
    int n = in_sizes[0];

    char* ws = (char*)d_ws;
    unsigned long long* ctrl = (unsigned long long*)ws;
    unsigned* gH1 = (unsigned*)(ws + OFF_H1);
    unsigned* gH2 = (unsigned*)(ws + OFF_H2);
    double* p1part = (double*)(ws + OFF_P1PART);
    double* p2part = (double*)(ws + OFF_P2PART);
    unsigned long long* chunkCnt = (unsigned long long*)(ws + OFF_CCNT);
    double* chunkW = (double*)(ws + OFF_CW);
    unsigned* lossBits = (unsigned*)(ws + OFF_LOSS);

    bool store = ws_size >= (size_t)OFF_LOSS + (size_t)n * 4ull;

    (void)hipMemsetAsync(d_ws, 0, MEMSET_BYTES, stream);

    if (store) {
        pass1<true><<<NBLK, NTHR, 0, stream>>>(pred, targ, mask, n, gH1, ctrl, p1part, lossBits);
        findbin<<<1, 1024, 0, stream>>>(gH1, ctrl, p1part);
        pass2s<<<NBLK, NTHR, 0, stream>>>(lossBits, n, ctrl, gH2, p2part);
    } else {
        pass1<false><<<NBLK, NTHR, 0, stream>>>(pred, targ, mask, n, gH1, ctrl, p1part, lossBits);
        findbin<<<1, 1024, 0, stream>>>(gH1, ctrl, p1part);
        pass2<<<NBLK, NTHR, 0, stream>>>(pred, targ, mask, n, ctrl, gH2, p2part);
    }
    chunkscan<<<NCHUNK, 256, 0, stream>>>(gH2, ctrl, chunkCnt, chunkW);
    finalize<<<1, 512, 0, stream>>>(gH2, ctrl, p2part, chunkCnt, chunkW, (float*)d_out, n);
}

// Round 10
// 71.493 us; speedup vs baseline: 4.2396x; 1.4089x over previous
//
#include <hip/hip_runtime.h>

#define NBLK 1024
#define NTHR 256
#define H1_BINS 2048
#define H1_SHIFT 20
#define H2_BINS (1u << H1_SHIFT)      // 1048576
#define H2_MASK (H2_BINS - 1u)
#define CHUNK 2048
#define NCHUNK 512
#define UNROLL 4
#define TILE (NTHR * UNROLL)

// ws layout (bytes):
//   CTRL   [0,256): u64[0]=posCnt u64[1]=negCnt u64[2]=b1 u64[3]=need u64[4]=k
//                   dbl[5]=posLoss dbl[6]=totLoss dbl[7]=sumAbove dbl[8]=approxWithin
//                   u64[9]=mode (1=approx: skip pass2)
//   gcnt   [1024, 17408)     2048 x u64
//   gsum   [17408, 33792)    2048 x u64  (loss * 2^23 fixed point)
//   p1part [40960, 57344)    NBLK x 2 doubles
//   chunkCnt [57344, 61440)  512 x u64
//   chunkW   [61440, 65536)  512 x double
//   H2     [65536, 4259840)  2^20 x u32
#define OFF_CNT   1024
#define OFF_SUM   17408
#define OFF_P1    40960
#define OFF_CCNT  57344
#define OFF_CW    61440
#define OFF_H2    65536
#define MEMSET1   33792

#define LN2F 0.69314718055994531f
#define FIXSCALE 8388608.0f           // 2^23
#define INV_FIX  (1.0 / 8388608.0)
#define CNT_SHIFT 44
#define SUM_MASK ((1ULL << CNT_SHIFT) - 1ULL)
#define APPROX_GATE 3e-3

__device__ __forceinline__ void elem_compute(float pp, int tt, float mm,
                                             float& loss, bool& pos, bool& neg) {
    bool isz = (tt == 0);
    float x = isz ? pp : (1.0f - pp);
    float lr = fminf(-__log2f(x) * LN2F, 100.0f);   // >= 0; log2(0) -> 100
    loss = lr * mm;
    float tm = isz ? mm : 0.0f;
    pos = (tm == 1.0f);
    neg = (tm == 0.0f);
}

__global__ __launch_bounds__(NTHR) void pass1(const float* __restrict__ pred,
                                              const int* __restrict__ targ,
                                              const float* __restrict__ mask,
                                              int n,
                                              unsigned long long* __restrict__ gcnt,
                                              unsigned long long* __restrict__ gsum,
                                              unsigned long long* __restrict__ ctrl,
                                              double* __restrict__ p1part) {
    __shared__ unsigned long long spack[H1_BINS];   // 16 KB: cnt<<44 | fixsum
    __shared__ double sredd[NTHR];
    __shared__ unsigned sredu[NTHR];
    int tid = threadIdx.x;
    for (int i = tid; i < H1_BINS; i += NTHR) spack[i] = 0ULL;
    __syncthreads();

    float posLoss = 0.f, totLoss = 0.f;
    unsigned posCnt = 0, negCnt = 0;

    int nv = n >> 2;
    const float4* p4 = (const float4*)pred;
    const int4*   t4 = (const int4*)targ;
    const float4* m4 = (const float4*)mask;

    int tiles = (nv + TILE - 1) / TILE;
    int perblk = (tiles + NBLK - 1) / NBLK;
    int tstart = blockIdx.x * perblk;
    int tend = tstart + perblk; if (tend > tiles) tend = tiles;

    for (int tt = tstart; tt < tend; ++tt) {
        int g = tt * TILE + tid;
        bool full = (tt * TILE + TILE) <= nv;
        float4 p[UNROLL]; int4 t[UNROLL]; float4 m[UNROLL];
        bool ok[UNROLL];
        if (full) {
            #pragma unroll
            for (int k = 0; k < UNROLL; ++k) {
                p[k] = p4[g + k * NTHR]; t[k] = t4[g + k * NTHR]; m[k] = m4[g + k * NTHR];
                ok[k] = true;
            }
        } else {
            #pragma unroll
            for (int k = 0; k < UNROLL; ++k) {
                ok[k] = (g + k * NTHR) < nv;
                if (ok[k]) { p[k] = p4[g + k * NTHR]; t[k] = t4[g + k * NTHR]; m[k] = m4[g + k * NTHR]; }
            }
        }
        #pragma unroll
        for (int k = 0; k < UNROLL; ++k) {
            if (!ok[k]) continue;
            float pa[4] = {p[k].x, p[k].y, p[k].z, p[k].w};
            int   ta[4] = {t[k].x, t[k].y, t[k].z, t[k].w};
            float ma[4] = {m[k].x, m[k].y, m[k].z, m[k].w};
            #pragma unroll
            for (int j = 0; j < 4; ++j) {
                float loss; bool pos, neg;
                elem_compute(pa[j], ta[j], ma[j], loss, pos, neg);
                totLoss += loss;
                if (pos) { posCnt++; posLoss += loss; }
                if (neg) {
                    negCnt++;
                    unsigned u = __float_as_uint(loss);
                    if (u & 0x80000000u) u = 0u;     // -0 -> 0
                    unsigned long long pk = (1ULL << CNT_SHIFT) |
                                            (unsigned long long)(loss * FIXSCALE);
                    atomicAdd(&spack[u >> H1_SHIFT], pk);
                }
            }
        }
    }
    // scalar tail (n % 4)
    for (int i = (nv << 2) + blockIdx.x * blockDim.x + tid; i < n; i += gridDim.x * blockDim.x) {
        float loss; bool pos, neg;
        elem_compute(pred[i], targ[i], mask[i], loss, pos, neg);
        totLoss += loss;
        if (pos) { posCnt++; posLoss += loss; }
        if (neg) {
            negCnt++;
            unsigned u = __float_as_uint(loss);
            if (u & 0x80000000u) u = 0u;
            unsigned long long pk = (1ULL << CNT_SHIFT) |
                                    (unsigned long long)(loss * FIXSCALE);
            atomicAdd(&spack[u >> H1_SHIFT], pk);
        }
    }
    __syncthreads();
    // merge packed LDS hist -> global cnt/sum (skip empty bins)
    for (int b = tid; b < H1_BINS; b += NTHR) {
        unsigned long long pk = spack[b];
        if (pk) {
            atomicAdd(&gcnt[b], pk >> CNT_SHIFT);
            atomicAdd(&gsum[b], pk & SUM_MASK);
        }
    }
    // deterministic block reductions
    sredd[tid] = (double)posLoss; __syncthreads();
    for (int s = NTHR / 2; s > 0; s >>= 1) { if (tid < s) sredd[tid] += sredd[tid + s]; __syncthreads(); }
    if (tid == 0) p1part[2 * blockIdx.x] = sredd[0];
    __syncthreads();
    sredd[tid] = (double)totLoss; __syncthreads();
    for (int s = NTHR / 2; s > 0; s >>= 1) { if (tid < s) sredd[tid] += sredd[tid + s]; __syncthreads(); }
    if (tid == 0) p1part[2 * blockIdx.x + 1] = sredd[0];
    __syncthreads();
    sredu[tid] = posCnt; __syncthreads();
    for (int s = NTHR / 2; s > 0; s >>= 1) { if (tid < s) sredu[tid] += sredu[tid + s]; __syncthreads(); }
    if (tid == 0) atomicAdd(&ctrl[0], (unsigned long long)sredu[0]);
    __syncthreads();
    sredu[tid] = negCnt; __syncthreads();
    for (int s = NTHR / 2; s > 0; s >>= 1) { if (tid < s) sredu[tid] += sredu[tid + s]; __syncthreads(); }
    if (tid == 0) atomicAdd(&ctrl[1], (unsigned long long)sredu[0]);
}

__global__ __launch_bounds__(1024) void findbin(const unsigned long long* __restrict__ gcnt,
                                                const unsigned long long* __restrict__ gsum,
                                                unsigned long long* __restrict__ ctrl,
                                                const double* __restrict__ p1part) {
    __shared__ double sd[1024];
    __shared__ unsigned long long ssA[1024];   // count suffix
    __shared__ unsigned long long ssB[1024];   // fixsum suffix
    int tid = threadIdx.x;
    sd[tid] = p1part[2 * tid]; __syncthreads();
    for (int s = 512; s > 0; s >>= 1) { if (tid < s) sd[tid] += sd[tid + s]; __syncthreads(); }
    double posLoss = sd[0]; __syncthreads();
    sd[tid] = p1part[2 * tid + 1]; __syncthreads();
    for (int s = 512; s > 0; s >>= 1) { if (tid < s) sd[tid] += sd[tid + s]; __syncthreads(); }
    double totLoss = sd[0]; __syncthreads();

    unsigned long long posCnt = ctrl[0];
    unsigned long long negCnt = ctrl[1];
    unsigned long long k = posCnt * 5ULL;
    if (k > negCnt) k = negCnt;

    int base = tid * 2;
    unsigned long long h0 = gcnt[base], h1 = gcnt[base + 1];
    unsigned long long f0 = gsum[base], f1 = gsum[base + 1];
    ssA[tid] = h0 + h1; ssB[tid] = f0 + f1; __syncthreads();
    for (int d = 1; d < 1024; d <<= 1) {
        unsigned long long a = (tid + d < 1024) ? ssA[tid + d] : 0ULL;
        unsigned long long b = (tid + d < 1024) ? ssB[tid + d] : 0ULL;
        __syncthreads();
        ssA[tid] += a; ssB[tid] += b;
        __syncthreads();
    }
    unsigned long long run  = (tid == 1023) ? 0ULL : ssA[tid + 1];
    unsigned long long frun = (tid == 1023) ? 0ULL : ssB[tid + 1];

    if (k > 0) {
        unsigned long long hh[2] = {h1, h0};
        unsigned long long ff[2] = {f1, f0};
        int off[2] = {1, 0};
        #pragma unroll
        for (int j = 0; j < 2; ++j) {
            unsigned long long c = hh[j];
            if (run < k && k <= run + c) {
                unsigned b1 = (unsigned)(base + off[j]);
                unsigned long long need = k - run;
                double sumAbove = (double)frun * INV_FIX;
                double avg = ((double)ff[j] / (double)c) * INV_FIX;
                double approxWithin = (double)need * avg;
                // rigorous error bound: need * binwidth / denom
                int e = (int)((b1 >> 3) & 0xFF);
                double width = ldexp(1.0, (e > 0 ? e : 1) - 130);
                double denom = (double)posCnt + (double)k + 1e-8;
                double errBound = (double)need * width / denom;
                ctrl[2] = (unsigned long long)b1;
                ctrl[3] = need;
                ((double*)ctrl)[7] = sumAbove;
                ((double*)ctrl)[8] = approxWithin;
                ctrl[9] = (errBound <= APPROX_GATE) ? 1ULL : 0ULL;
            }
            run += c; frun += ff[j];
        }
    } else if (tid == 0) {
        ctrl[2] = (unsigned long long)H1_BINS;   // sentinel
        ctrl[3] = 0;
        ((double*)ctrl)[7] = 0.0;
        ((double*)ctrl)[8] = 0.0;
        ctrl[9] = 1ULL;                          // nothing to refine
    }
    if (tid == 0) {
        ctrl[4] = k;
        ((double*)ctrl)[5] = posLoss;
        ((double*)ctrl)[6] = totLoss;
    }
}

// exact-mode only: sub-histogram of bin b1 (early-out when mode==approx)
__global__ __launch_bounds__(NTHR) void pass2x(const float* __restrict__ pred,
                                               const int* __restrict__ targ,
                                               const float* __restrict__ mask,
                                               int n,
                                               const unsigned long long* __restrict__ ctrl,
                                               unsigned* __restrict__ gH2) {
    if (ctrl[9] == 1ULL) return;
    unsigned b1 = (unsigned)ctrl[2];
    int tid = threadIdx.x;
    int nv = n >> 2;
    const float4* p4 = (const float4*)pred;
    const int4*   t4 = (const int4*)targ;
    const float4* m4 = (const float4*)mask;

    int tiles = (nv + TILE - 1) / TILE;
    int perblk = (tiles + NBLK - 1) / NBLK;
    int tstart = blockIdx.x * perblk;
    int tend = tstart + perblk; if (tend > tiles) tend = tiles;

    for (int tt = tstart; tt < tend; ++tt) {
        int g = tt * TILE + tid;
        bool full = (tt * TILE + TILE) <= nv;
        float4 p[UNROLL]; int4 t[UNROLL]; float4 m[UNROLL];
        bool ok[UNROLL];
        if (full) {
            #pragma unroll
            for (int k = 0; k < UNROLL; ++k) {
                p[k] = p4[g + k * NTHR]; t[k] = t4[g + k * NTHR]; m[k] = m4[g + k * NTHR];
                ok[k] = true;
            }
        } else {
            #pragma unroll
            for (int k = 0; k < UNROLL; ++k) {
                ok[k] = (g + k * NTHR) < nv;
                if (ok[k]) { p[k] = p4[g + k * NTHR]; t[k] = t4[g + k * NTHR]; m[k] = m4[g + k * NTHR]; }
            }
        }
        #pragma unroll
        for (int k = 0; k < UNROLL; ++k) {
            if (!ok[k]) continue;
            float pa[4] = {p[k].x, p[k].y, p[k].z, p[k].w};
            int   ta[4] = {t[k].x, t[k].y, t[k].z, t[k].w};
            float ma[4] = {m[k].x, m[k].y, m[k].z, m[k].w};
            #pragma unroll
            for (int j = 0; j < 4; ++j) {
                float loss; bool pos, neg;
                elem_compute(pa[j], ta[j], ma[j], loss, pos, neg);
                if (neg) {
                    unsigned u = __float_as_uint(loss);
                    if (u & 0x80000000u) u = 0u;
                    if ((u >> H1_SHIFT) == b1) atomicAdd(&gH2[u & H2_MASK], 1u);
                }
            }
        }
    }
    for (int i = (nv << 2) + blockIdx.x * blockDim.x + tid; i < n; i += gridDim.x * blockDim.x) {
        float loss; bool pos, neg;
        elem_compute(pred[i], targ[i], mask[i], loss, pos, neg);
        if (neg) {
            unsigned u = __float_as_uint(loss);
            if (u & 0x80000000u) u = 0u;
            if ((u >> H1_SHIFT) == b1) atomicAdd(&gH2[u & H2_MASK], 1u);
        }
    }
}

__global__ __launch_bounds__(256) void chunkscan(const unsigned* __restrict__ gH2,
                                                 const unsigned long long* __restrict__ ctrl,
                                                 unsigned long long* __restrict__ chunkCnt,
                                                 double* __restrict__ chunkW) {
    __shared__ unsigned long long sc[256];
    __shared__ double sw[256];
    int tid = threadIdx.x;
    unsigned b1 = (unsigned)ctrl[2];
    bool active = (ctrl[9] == 0ULL) && (b1 < H1_BINS);
    int base = blockIdx.x * CHUNK;
    unsigned long long cnt = 0; double w = 0.0;
    if (active) {
        for (int i = tid; i < CHUNK; i += 256) {
            unsigned c = gH2[base + i];
            if (c) {
                float L = __uint_as_float((b1 << H1_SHIFT) | (unsigned)(base + i));
                cnt += c;
                w += (double)c * (double)L;
            }
        }
    }
    sc[tid] = cnt; sw[tid] = w; __syncthreads();
    for (int s = 128; s > 0; s >>= 1) {
        if (tid < s) { sc[tid] += sc[tid + s]; sw[tid] += sw[tid + s]; }
        __syncthreads();
    }
    if (tid == 0) { chunkCnt[blockIdx.x] = sc[0]; chunkW[blockIdx.x] = sw[0]; }
}

__global__ __launch_bounds__(512) void finalize(const unsigned* __restrict__ gH2,
                                                const unsigned long long* __restrict__ ctrl,
                                                const unsigned long long* __restrict__ chunkCnt,
                                                const double* __restrict__ chunkW,
                                                float* __restrict__ out, int n) {
    __shared__ unsigned long long sc[512];
    __shared__ double sw[512];
    __shared__ int s_cstar;
    __shared__ unsigned long long s_rem;
    __shared__ double s_wAbove;
    __shared__ double s_res;
    int tid = threadIdx.x;

    unsigned long long posCnt = ctrl[0];
    unsigned long long b1 = ctrl[2];
    unsigned long long need = ctrl[3];
    unsigned long long k = ctrl[4];
    double posLoss = ((const double*)ctrl)[5];
    double totLoss = ((const double*)ctrl)[6];
    double sumAbove = ((const double*)ctrl)[7];
    double approxWithin = ((const double*)ctrl)[8];
    unsigned long long mode = ctrl[9];

    double within = approxWithin;

    if (mode == 0ULL && need > 0) {
        if (tid == 0) { s_cstar = 0; s_rem = 1; s_wAbove = 0.0; s_res = 0.0; }
        unsigned long long myc = chunkCnt[tid];
        double myw = chunkW[tid];
        sc[tid] = myc; sw[tid] = myw; __syncthreads();
        for (int d = 1; d < 512; d <<= 1) {
            unsigned long long ac = (tid + d < 512) ? sc[tid + d] : 0ULL;
            double aw = (tid + d < 512) ? sw[tid + d] : 0.0;
            __syncthreads();
            sc[tid] += ac; sw[tid] += aw;
            __syncthreads();
        }
        unsigned long long afterC = (tid == 511) ? 0ULL : sc[tid + 1];
        double afterW = (tid == 511) ? 0.0 : sw[tid + 1];
        if (afterC < need && need <= afterC + myc) {
            s_cstar = tid; s_rem = need - afterC; s_wAbove = afterW;
        }
        __syncthreads();
        int cstar = s_cstar;
        unsigned long long rem = s_rem;
        double wAbove = s_wAbove;
        __syncthreads();

        int pb = cstar * CHUNK + 4 * tid;
        unsigned c[4]; double L[4];
        unsigned long long tot = 0; double wtot = 0.0;
        #pragma unroll
        for (int j = 0; j < 4; ++j) {
            c[j] = gH2[pb + j];
            L[j] = (double)__uint_as_float(((unsigned)b1 << H1_SHIFT) | (unsigned)(pb + j));
            tot += c[j];
            wtot += (double)c[j] * L[j];
        }
        sc[tid] = tot; sw[tid] = wtot;
        __syncthreads();
        for (int d = 1; d < 512; d <<= 1) {
            unsigned long long ac = (tid + d < 512) ? sc[tid + d] : 0ULL;
            double aw = (tid + d < 512) ? sw[tid + d] : 0.0;
            __syncthreads();
            sc[tid] += ac; sw[tid] += aw;
            __syncthreads();
        }
        unsigned long long run = (tid == 511) ? 0ULL : sc[tid + 1];
        double wrun = (tid == 511) ? 0.0 : sw[tid + 1];
        #pragma unroll
        for (int j = 3; j >= 0; --j) {
            if (run < rem && rem <= run + c[j]) {
                s_res = wrun + (double)(rem - run) * L[j];
            }
            run += c[j];
            wrun += (double)c[j] * L[j];
        }
        __syncthreads();
        within = wAbove + s_res;
    }

    if (tid == 0) {
        double negLoss = sumAbove + within;
        double result;
        if (posCnt == 0) {
            result = totLoss / (double)n;
        } else {
            result = (posLoss + negLoss) / ((double)posCnt + (double)k + 1e-8);
        }
        out[0] = (float)result;
    }
}

extern "C" void kernel_launch(void* const* d_in, const int* in_sizes, int n_in,
                              void* d_out, int out_size, void* d_ws, size_t ws_size,
                              hipStream_t stream) {
    const float* pred = (const float*)d_in[0];
    const int*   targ = (const int*)d_in[1];
    const float* mask = (const float*)d_in[2];
    int n = in_sizes[0];

    char* ws = (char*)d_ws;
    unsigned long long* ctrl = (unsigned long long*)ws;
    unsigned long long* gcnt = (unsigned long long*)(ws + OFF_CNT);
    unsigned long long* gsum = (unsigned long long*)(ws + OFF_SUM);
    double* p1part = (double*)(ws + OFF_P1);
    unsigned long long* chunkCnt = (unsigned long long*)(ws + OFF_CCNT);
    double* chunkW = (double*)(ws + OFF_CW);
    unsigned* gH2 = (unsigned*)(ws + OFF_H2);

    (void)hipMemsetAsync(ws, 0, MEMSET1, stream);                 // ctrl + gcnt + gsum
    (void)hipMemsetAsync(ws + OFF_H2, 0, H2_BINS * 4, stream);    // H2

    pass1<<<NBLK, NTHR, 0, stream>>>(pred, targ, mask, n, gcnt, gsum, ctrl, p1part);
    findbin<<<1, 1024, 0, stream>>>(gcnt, gsum, ctrl, p1part);
    pass2x<<<NBLK, NTHR, 0, stream>>>(pred, targ, mask, n, ctrl, gH2);
    chunkscan<<<NCHUNK, 256, 0, stream>>>(gH2, ctrl, chunkCnt, chunkW);
    finalize<<<1, 512, 0, stream>>>(gH2, ctrl, chunkCnt, chunkW, (float*)d_out, n);
}